// Round 1
// baseline (176.750 us; speedup 1.0000x reference)
//
#include <hip/hip_runtime.h>
#include <hip/hip_bf16.h>

#define NN 2048   // n_nodes
#define CC 512    // channels
#define KT 8      // Taylor terms (rho(tL)~0.2 -> tail ~1e-12)

typedef __bf16 bf16x8 __attribute__((ext_vector_type(8)));
typedef float  f32x4  __attribute__((ext_vector_type(4)));
typedef int    i32x4  __attribute__((ext_vector_type(4)));
typedef unsigned short u16x4 __attribute__((ext_vector_type(4)));

__device__ __forceinline__ unsigned short f2bf(float f) {
    unsigned int u = __builtin_bit_cast(unsigned int, f);
    u += 0x7FFFu + ((u >> 16) & 1u);
    return (unsigned short)(u >> 16);
}

// ---- L (f32 [2048][2048]) -> bf16, 4 elems/thread ----
__global__ void cast_L_kernel(const float* __restrict__ L,
                              unsigned short* __restrict__ Lbf) {
    size_t i = ((size_t)blockIdx.x * 256 + threadIdx.x) * 4;
    f32x4 v = *(const f32x4*)(L + i);
    u16x4 o;
    o[0] = f2bf(v[0]); o[1] = f2bf(v[1]); o[2] = f2bf(v[2]); o[3] = f2bf(v[3]);
    *(u16x4*)(Lbf + i) = o;
}

// ---- x [2048][512] f32 -> vT bf16 [512][2048] and yT f32 [512][2048] ----
__global__ void init_xT_kernel(const float* __restrict__ x,
                               unsigned short* __restrict__ vbf,
                               float* __restrict__ yT) {
    __shared__ float tile[64][65];
    const int bi = blockIdx.x;   // node tile 0..31
    const int bc = blockIdx.y;   // channel tile 0..7
    const int tid = threadIdx.x;
    #pragma unroll
    for (int rr = 0; rr < 16; ++rr) {
        int r = (tid >> 6) + rr * 4;      // node-local
        int c = tid & 63;                 // chan-local
        tile[r][c] = x[(size_t)(bi * 64 + r) * CC + bc * 64 + c];
    }
    __syncthreads();
    #pragma unroll
    for (int rr = 0; rr < 16; ++rr) {
        int cc = (tid >> 6) + rr * 4;     // chan-local (row of xT)
        int r  = tid & 63;                // node-local (col of xT)
        float v = tile[r][cc];
        size_t addr = (size_t)(bc * 64 + cc) * NN + bi * 64 + r;
        yT[addr]  = v;
        vbf[addr] = f2bf(v);
    }
}

// ---- one Taylor term: wT = vT @ L (bf16 MFMA), fused epilogue:
//      v_new = (-t/k)*wT ; yT += v_new ; vout = bf16(v_new) ----
__global__ __launch_bounds__(256)
void gemm_step_kernel(const unsigned short* __restrict__ A,   // vT_bf [512][2048]
                      const unsigned short* __restrict__ B,   // Lbf   [2048][2048] (symmetric)
                      float* __restrict__ yT,                 // [512][2048]
                      unsigned short* __restrict__ vout,      // [512][2048]
                      const float* __restrict__ tptr,
                      int kterm) {
    __shared__ short As[64 * 64];  // [m][k] swizzled
    __shared__ short Bs[64 * 64];  // [n][k] swizzled

    const int tid  = threadIdx.x;
    const int lane = tid & 63;
    const int wid  = tid >> 6;     // 0..3
    const int wr   = wid >> 1;     // m half (0..1)
    const int wc   = wid & 1;      // n half (0..1)

    const int n0 = blockIdx.x * 64;  // i dim (0..2047)
    const int m0 = blockIdx.y * 64;  // c dim (0..511)

    f32x4 acc[2][2] = {};

    i32x4 ra[2], rb[2];
    // granule s (0..511): row = s>>3 (tile row), kb = s&7 (16B k-block)
    auto load_tiles = [&](int k0) {
        #pragma unroll
        for (int h = 0; h < 2; ++h) {
            int s = tid + h * 256;
            int row = s >> 3, kb = s & 7;
            ra[h] = *(const i32x4*)(A + ((size_t)(m0 + row) * NN + k0 + kb * 8));
            rb[h] = *(const i32x4*)(B + ((size_t)(n0 + row) * NN + k0 + kb * 8));
        }
    };

    load_tiles(0);
    for (int k0 = 0; k0 < NN; k0 += 64) {
        __syncthreads();   // previous tile fully consumed
        #pragma unroll
        for (int h = 0; h < 2; ++h) {
            int s = tid + h * 256;
            int row = s >> 3, kb = s & 7;
            int g = (row << 3) + (kb ^ (row & 7));   // XOR swizzle
            *(i32x4*)&As[g * 8] = ra[h];
            *(i32x4*)&Bs[g * 8] = rb[h];
        }
        __syncthreads();
        if (k0 + 64 < NN) load_tiles(k0 + 64);   // prefetch next tile into regs

        #pragma unroll
        for (int kk = 0; kk < 2; ++kk) {
            bf16x8 af[2], bfr[2];
            #pragma unroll
            for (int f = 0; f < 2; ++f) {
                int m  = wr * 32 + f * 16 + (lane & 15);
                int kb = kk * 4 + (lane >> 4);
                i32x4 a = *(const i32x4*)&As[((m << 3) + (kb ^ (m & 7))) * 8];
                af[f] = __builtin_bit_cast(bf16x8, a);
                int n = wc * 32 + f * 16 + (lane & 15);
                i32x4 b = *(const i32x4*)&Bs[((n << 3) + (kb ^ (n & 7))) * 8];
                bfr[f] = __builtin_bit_cast(bf16x8, b);
            }
            #pragma unroll
            for (int fm = 0; fm < 2; ++fm)
                #pragma unroll
                for (int fn = 0; fn < 2; ++fn)
                    acc[fm][fn] = __builtin_amdgcn_mfma_f32_16x16x32_bf16(
                        af[fm], bfr[fn], acc[fm][fn], 0, 0, 0);
        }
    }

    float tt = tptr[0];
    tt = fmaxf(tt, 1e-8f);
    const float coef = -tt / (float)kterm;

    // C/D layout (m89): col = lane&15, row = (lane>>4)*4 + reg
    #pragma unroll
    for (int fm = 0; fm < 2; ++fm) {
        #pragma unroll
        for (int fn = 0; fn < 2; ++fn) {
            int n_g    = n0 + wc * 32 + fn * 16 + (lane & 15);
            int m_base = m0 + wr * 32 + fm * 16 + ((lane >> 4) << 2);
            #pragma unroll
            for (int r = 0; r < 4; ++r) {
                float v = coef * acc[fm][fn][r];
                size_t addr = (size_t)(m_base + r) * NN + n_g;
                yT[addr] += v;
                vout[addr] = f2bf(v);
            }
        }
    }
}

// ---- yT [512][2048] -> out [2048][512] ----
__global__ void final_T_kernel(const float* __restrict__ yT,
                               float* __restrict__ out) {
    __shared__ float tile[64][65];
    const int bi = blockIdx.x;   // node tile
    const int bc = blockIdx.y;   // chan tile
    const int tid = threadIdx.x;
    #pragma unroll
    for (int rr = 0; rr < 16; ++rr) {
        int cloc = (tid >> 6) + rr * 4;
        int iloc = tid & 63;
        tile[cloc][iloc] = yT[(size_t)(bc * 64 + cloc) * NN + bi * 64 + iloc];
    }
    __syncthreads();
    #pragma unroll
    for (int rr = 0; rr < 16; ++rr) {
        int iloc = (tid >> 6) + rr * 4;
        int cloc = tid & 63;
        out[(size_t)(bi * 64 + iloc) * CC + bc * 64 + cloc] = tile[cloc][iloc];
    }
}

extern "C" void kernel_launch(void* const* d_in, const int* in_sizes, int n_in,
                              void* d_out, int out_size, void* d_ws, size_t ws_size,
                              hipStream_t stream) {
    (void)in_sizes; (void)n_in; (void)out_size; (void)ws_size;
    const float* x = (const float*)d_in[0];
    const float* L = (const float*)d_in[1];
    const float* t = (const float*)d_in[2];
    float* out = (float*)d_out;

    char* ws = (char*)d_ws;
    unsigned short* Lbf = (unsigned short*)ws;                   // 8 MB
    unsigned short* vA  = (unsigned short*)(ws + (8  << 20));    // 2 MB
    unsigned short* vB  = (unsigned short*)(ws + (10 << 20));    // 2 MB
    float*          yT  = (float*)        (ws + (12 << 20));     // 4 MB

    cast_L_kernel<<<(NN * NN / 4) / 256, 256, 0, stream>>>(L, Lbf);
    init_xT_kernel<<<dim3(NN / 64, CC / 64), 256, 0, stream>>>(x, vA, yT);

    unsigned short* cur = vA;
    unsigned short* nxt = vB;
    for (int k = 1; k <= KT; ++k) {
        gemm_step_kernel<<<dim3(NN / 64, CC / 64), 256, 0, stream>>>(
            cur, Lbf, yT, nxt, t, k);
        unsigned short* tmp = cur; cur = nxt; nxt = tmp;
    }
    final_T_kernel<<<dim3(NN / 64, CC / 64), 256, 0, stream>>>(yT, out);
}

// Round 2
// 105.313 us; speedup vs baseline: 1.6783x; 1.6783x over previous
//
#include <hip/hip_runtime.h>
#include <hip/hip_bf16.h>

#define NN 2048   // n_nodes
#define CC 512    // channels
#define KT 4      // Taylor terms: rho(tL)<=0.201 -> deg-4 remainder ~3e-6 (negligible vs bf16)

typedef __bf16 bf16x8 __attribute__((ext_vector_type(8)));
typedef float  f32x4  __attribute__((ext_vector_type(4)));
typedef int    i32x4  __attribute__((ext_vector_type(4)));
typedef unsigned short u16x4 __attribute__((ext_vector_type(4)));

#define GLD_LDS16(gptr, lptr)                                                        \
    __builtin_amdgcn_global_load_lds(                                                \
        (const __attribute__((address_space(1))) void*)(gptr),                       \
        (__attribute__((address_space(3))) void*)(lptr), 16, 0, 0)

__device__ __forceinline__ unsigned short f2bf(float f) {
    unsigned int u = __builtin_bit_cast(unsigned int, f);
    u += 0x7FFFu + ((u >> 16) & 1u);
    return (unsigned short)(u >> 16);
}

// ---- L (f32 [2048][2048]) -> bf16 ----
__global__ void cast_L_kernel(const float* __restrict__ L,
                              unsigned short* __restrict__ Lbf) {
    size_t i = ((size_t)blockIdx.x * 256 + threadIdx.x) * 4;
    f32x4 v = *(const f32x4*)(L + i);
    u16x4 o;
    o[0] = f2bf(v[0]); o[1] = f2bf(v[1]); o[2] = f2bf(v[2]); o[3] = f2bf(v[3]);
    *(u16x4*)(Lbf + i) = o;
}

// ---- x [2048][512] f32 -> vT bf16 [512][2048] and yT f32 [512][2048] ----
__global__ void init_xT_kernel(const float* __restrict__ x,
                               unsigned short* __restrict__ vbf,
                               float* __restrict__ yT) {
    __shared__ float tile[64][65];
    const int bi = blockIdx.x;   // node tile 0..31
    const int bc = blockIdx.y;   // channel tile 0..7
    const int tid = threadIdx.x;
    #pragma unroll
    for (int rr = 0; rr < 16; ++rr) {
        int r = (tid >> 6) + rr * 4;      // node-local
        int c = tid & 63;                 // chan-local
        tile[r][c] = x[(size_t)(bi * 64 + r) * CC + bc * 64 + c];
    }
    __syncthreads();
    #pragma unroll
    for (int rr = 0; rr < 16; ++rr) {
        int cc = (tid >> 6) + rr * 4;     // chan-local (row of xT)
        int r  = tid & 63;                // node-local (col of xT)
        float v = tile[r][cc];
        size_t addr = (size_t)(bc * 64 + cc) * NN + bi * 64 + r;
        yT[addr]  = v;
        vbf[addr] = f2bf(v);
    }
}

// ---- one Taylor term: wT = vT @ L (bf16 MFMA, L symmetric so both operands row-read)
//      4-deep global_load_lds pipeline, counted vmcnt, raw barriers.
//      LAST=0 epilogue: v = coef*wT; yT += v; vout = bf16(v)
//      LAST=1 epilogue: out[n][c] = yT + coef*wT  (transposed via LDS, coalesced) ----
template <int LAST>
__global__ __launch_bounds__(256)
void gemm_step_kernel(const unsigned short* __restrict__ A,   // vT_bf [512][2048]
                      const unsigned short* __restrict__ B,   // Lbf   [2048][2048]
                      float* __restrict__ yT,                 // [512][2048]
                      unsigned short* __restrict__ vout,      // [512][2048]
                      float* __restrict__ out,                // [2048][512] (LAST)
                      const float* __restrict__ tptr,
                      int kterm) {
    // LDS granule = 8 shorts (16B). Tile = 512 granules (64 rows x 8 k-blocks).
    // Granule (row, c) holds global (row, c ^ (row&7))  -- same involution as read side.
    __shared__ short As[4][64 * 64];
    __shared__ short Bs[4][64 * 64];

    const int tid  = threadIdx.x;
    const int lane = tid & 63;
    const int wid  = tid >> 6;     // 0..3
    const int wr   = wid >> 1;     // m half
    const int wc   = wid & 1;      // n half

    const int n0 = blockIdx.x * 64;  // node dim
    const int m0 = blockIdx.y * 64;  // channel dim

    // per-lane source mapping for global_load_lds (dest is linear: granule = h*256+wid*64+lane)
    int rowg[2], colg[2];
    #pragma unroll
    for (int h = 0; h < 2; ++h) {
        int g = h * 256 + wid * 64 + lane;
        rowg[h] = g >> 3;
        colg[h] = (g & 7) ^ (rowg[h] & 7);
    }

    auto issue_tile = [&](int kt, int buf) {
        #pragma unroll
        for (int h = 0; h < 2; ++h) {
            const unsigned short* sa = A + (size_t)(m0 + rowg[h]) * NN + kt * 64 + colg[h] * 8;
            const unsigned short* sb = B + (size_t)(n0 + rowg[h]) * NN + kt * 64 + colg[h] * 8;
            GLD_LDS16(sa, &As[buf][(h * 256 + wid * 64) * 8]);
            GLD_LDS16(sb, &Bs[buf][(h * 256 + wid * 64) * 8]);
        }
    };

    f32x4 acc[2][2] = {};

    // prologue: 3 tiles in flight (12 loads/wave)
    issue_tile(0, 0);
    issue_tile(1, 1);
    issue_tile(2, 2);

    for (int t = 0; t < NN / 64; ++t) {
        // wait for tile t's loads (leave t+1,t+2 in flight), then sync all waves
        if (t < 30)       asm volatile("s_waitcnt vmcnt(8)\n\ts_barrier" ::: "memory");
        else if (t == 30) asm volatile("s_waitcnt vmcnt(4)\n\ts_barrier" ::: "memory");
        else              asm volatile("s_waitcnt vmcnt(0)\n\ts_barrier" ::: "memory");

        if (t + 3 < NN / 64) issue_tile(t + 3, (t + 3) & 3);  // buf read at iter t-1: free

        const int buf = t & 3;
        #pragma unroll
        for (int kk = 0; kk < 2; ++kk) {
            bf16x8 af[2], bfr[2];
            #pragma unroll
            for (int f = 0; f < 2; ++f) {
                int m  = wr * 32 + f * 16 + (lane & 15);
                int kb = kk * 4 + (lane >> 4);
                i32x4 a = *(const i32x4*)&As[buf][((m << 3) + (kb ^ (m & 7))) * 8];
                af[f] = __builtin_bit_cast(bf16x8, a);
                int n = wc * 32 + f * 16 + (lane & 15);
                i32x4 b = *(const i32x4*)&Bs[buf][((n << 3) + (kb ^ (n & 7))) * 8];
                bfr[f] = __builtin_bit_cast(bf16x8, b);
            }
            #pragma unroll
            for (int fm = 0; fm < 2; ++fm)
                #pragma unroll
                for (int fn = 0; fn < 2; ++fn)
                    acc[fm][fn] = __builtin_amdgcn_mfma_f32_16x16x32_bf16(
                        af[fm], bfr[fn], acc[fm][fn], 0, 0, 0);
        }
    }

    float tt = fmaxf(tptr[0], 1e-8f);
    const float coef = -tt / (float)kterm;

    // C/D layout: col = lane&15, row = (lane>>4)*4 + reg
    if (!LAST) {
        #pragma unroll
        for (int fm = 0; fm < 2; ++fm) {
            #pragma unroll
            for (int fn = 0; fn < 2; ++fn) {
                int n_g    = n0 + wc * 32 + fn * 16 + (lane & 15);
                int m_base = m0 + wr * 32 + fm * 16 + ((lane >> 4) << 2);
                #pragma unroll
                for (int r = 0; r < 4; ++r) {
                    float v = coef * acc[fm][fn][r];
                    size_t addr = (size_t)(m_base + r) * NN + n_g;
                    yT[addr] += v;
                    vout[addr] = f2bf(v);
                }
            }
        }
    } else {
        // fused final transpose: stage y = yT + v in LDS (reuse As), write out coalesced
        float (*ot)[66] = (float (*)[66]) & As[0][0];   // 64x66 f32 = 16.9KB <= 32KB
        __syncthreads();                                // all MFMA LDS reads done
        #pragma unroll
        for (int fm = 0; fm < 2; ++fm) {
            #pragma unroll
            for (int fn = 0; fn < 2; ++fn) {
                int n_loc = wc * 32 + fn * 16 + (lane & 15);
                int m_loc = wr * 32 + fm * 16 + ((lane >> 4) << 2);
                #pragma unroll
                for (int r = 0; r < 4; ++r) {
                    float v = coef * acc[fm][fn][r];
                    size_t addr = (size_t)(m0 + m_loc + r) * NN + (n0 + n_loc);
                    ot[n_loc][m_loc + r] = yT[addr] + v;
                }
            }
        }
        __syncthreads();
        #pragma unroll
        for (int rr = 0; rr < 16; ++rr) {
            int e = rr * 256 + tid;
            int nloc = e >> 6, mloc = e & 63;
            out[(size_t)(n0 + nloc) * CC + m0 + mloc] = ot[nloc][mloc];
        }
    }
}

extern "C" void kernel_launch(void* const* d_in, const int* in_sizes, int n_in,
                              void* d_out, int out_size, void* d_ws, size_t ws_size,
                              hipStream_t stream) {
    (void)in_sizes; (void)n_in; (void)out_size; (void)ws_size;
    const float* x = (const float*)d_in[0];
    const float* L = (const float*)d_in[1];
    const float* t = (const float*)d_in[2];
    float* out = (float*)d_out;

    char* ws = (char*)d_ws;
    unsigned short* Lbf = (unsigned short*)ws;                   // 8 MB
    unsigned short* vA  = (unsigned short*)(ws + (8  << 20));    // 2 MB
    unsigned short* vB  = (unsigned short*)(ws + (10 << 20));    // 2 MB
    float*          yT  = (float*)        (ws + (12 << 20));     // 4 MB

    cast_L_kernel<<<(NN * NN / 4) / 256, 256, 0, stream>>>(L, Lbf);
    init_xT_kernel<<<dim3(NN / 64, CC / 64), 256, 0, stream>>>(x, vA, yT);

    dim3 grid(NN / 64, CC / 64);
    gemm_step_kernel<0><<<grid, 256, 0, stream>>>(vA, Lbf, yT, vB, nullptr, t, 1);
    gemm_step_kernel<0><<<grid, 256, 0, stream>>>(vB, Lbf, yT, vA, nullptr, t, 2);
    gemm_step_kernel<0><<<grid, 256, 0, stream>>>(vA, Lbf, yT, vB, nullptr, t, 3);
    gemm_step_kernel<1><<<grid, 256, 0, stream>>>(vB, Lbf, yT, nullptr, out, t, 4);
}